// Round 4
// baseline (224.955 us; speedup 1.0000x reference)
//
#include <hip/hip_runtime.h>
#include <hip/hip_cooperative_groups.h>

namespace cg = cooperative_groups;

#define NB 8
#define NS 4096
#define ND 768

// packed-f4 layout in wpack / LDS (units of float4):
//   [0,1536)    panel weights  : o*192 + i
//   [1536,4608) dialog weights : 1536 + o*384 + i  (+192 = parent half)
//   [4608,6144) char weights   : 4608 + o*384 + i  (+192 = parent half)
//   [6144,6336) lng | [6336,6528) lnb | [6528,6720) this block's sprj row
#define WPACK_F4 6528
#define LDS_F4   6720

typedef float4 f4;

static __device__ __forceinline__ f4 ld4(const float* __restrict__ p, int i) {
    return ((const f4*)p)[i];
}

static __device__ __forceinline__ void dot4(float& acc, const f4& a, const f4& w) {
    acc = fmaf(a.x, w.x, acc);
    acc = fmaf(a.y, w.y, acc);
    acc = fmaf(a.z, w.z, acc);
    acc = fmaf(a.w, w.w, acc);
}

// ---------------------------------------------------------------------------
// One cooperative kernel, 4 phases separated by grid.sync():
//   P0: pack head weights+ln into wpack (blocks 0..6), zero table (block 6),
//       style projection (block 7).
//   P1: scatter-max parent table; stage wpack+sprj row into LDS.
//   P2: parent panel feats -> pfeat (blocks 0..31, one wave per slot).
//   P3: main: 8 rounds x 16 waves, one token per wave (round-3 pipeline).
// mode: 0 = cooperative all-phases; 1..4 = standalone phase (fallback path).
// ---------------------------------------------------------------------------
__global__ __launch_bounds__(1024) void lp_all(
    const int* __restrict__ et, const int* __restrict__ ei, const int* __restrict__ ppi,
    const float* __restrict__ sv,
    const float* __restrict__ temb, const float* __restrict__ iemb,
    const float* __restrict__ pemb,
    const float* __restrict__ sw, const float* __restrict__ sb,
    const float* __restrict__ lng, const float* __restrict__ lnb,
    const float* __restrict__ pw, const float* __restrict__ pb,
    const float* __restrict__ dw, const float* __restrict__ db,
    const float* __restrict__ cw, const float* __restrict__ cb,
    int* __restrict__ table, float* __restrict__ sprj,
    float* __restrict__ wpack, float* __restrict__ pfeat,
    float* __restrict__ out, int mode)
{
    __shared__ f4 S[LDS_F4];                 // 107,520 B
    const int tid = threadIdx.x;
    const int lane = tid & 63;
    const int wid = tid >> 6;                // 0..15
    const int bx = blockIdx.x;
    const bool coop = (mode == 0);

    // ---------------- P0: pack + zero table + style projection ------------
    if (coop || mode == 1) {
        int q = bx * 1024 + tid;
        if (q < WPACK_F4) {
            f4 r;
            if (q < 1536) {                                  // panel: 8 x 192
                int o = q / 192, i = q - o * 192, d0 = 4 * i;
                r.x = pw[(d0+0)*8 + o];
                r.y = pw[(d0+1)*8 + o];
                r.z = pw[(d0+2)*8 + o];
                r.w = pw[(d0+3)*8 + o];
            } else if (q < 4608) {                           // dialog: 8 x 384
                int u = q - 1536;
                int o = u / 384, i = u - o * 384;
                int d0 = (i < 192) ? 4*i : 768 + 4*(i - 192);
                r.x = dw[(d0+0)*8 + o];
                r.y = dw[(d0+1)*8 + o];
                r.z = dw[(d0+2)*8 + o];
                r.w = dw[(d0+3)*8 + o];
            } else if (q < 6144) {                           // char: 4 x 384
                int u = q - 4608;
                int o = u / 384, i = u - o * 384;
                int d0 = (i < 192) ? 4*i : 768 + 4*(i - 192);
                r.x = cw[(d0+0)*4 + o];
                r.y = cw[(d0+1)*4 + o];
                r.z = cw[(d0+2)*4 + o];
                r.w = cw[(d0+3)*4 + o];
            } else if (q < 6336) {
                r = ld4(lng, q - 6144);
            } else {
                r = ld4(lnb, q - 6336);
            }
            ((f4*)wpack)[q] = r;
        } else if (q < WPACK_F4 + NB * 64) {
            table[q - WPACK_F4] = -1;                        // init parent table
        }
        if (bx == 7 && wid < 8) {                            // style projection
            const int b = wid;
            const float sv0 = sv[b*4+0], sv1 = sv[b*4+1], sv2 = sv[b*4+2], sv3 = sv[b*4+3];
            #pragma unroll
            for (int g = 0; g < 3; ++g) {
                int i = g*64 + lane;
                f4 w0 = ld4(sw, i), w1 = ld4(sw, 192+i), w2 = ld4(sw, 384+i), w3 = ld4(sw, 576+i);
                f4 bb = ld4(sb, i);
                f4 r;
                r.x = bb.x + sv0*w0.x + sv1*w1.x + sv2*w2.x + sv3*w3.x;
                r.y = bb.y + sv0*w0.y + sv1*w1.y + sv2*w2.y + sv3*w3.y;
                r.z = bb.z + sv0*w0.z + sv1*w1.z + sv2*w2.z + sv3*w3.z;
                r.w = bb.w + sv0*w0.w + sv1*w1.w + sv2*w2.w + sv3*w3.w;
                ((f4*)(sprj + b*ND))[i] = r;
            }
        }
    }
    if (coop) cg::this_grid().sync();

    // ---------------- P1: scatter-max + LDS staging ------------------------
    if (coop || mode == 2) {
        int gt = bx * 1024 + tid;
        if (gt < NB * NS && et[gt] == 1)
            atomicMax(&table[(gt >> 12) * 64 + ei[gt]], gt & (NS - 1));
    }
    if (coop || mode >= 3) {
        for (int i = tid; i < WPACK_F4; i += 1024) S[i] = ((const f4*)wpack)[i];
        if (tid < 192) S[WPACK_F4 + tid] = ((const f4*)(sprj + (bx >> 5) * ND))[tid];
        __syncthreads();
    }
    if (coop) cg::this_grid().sync();

    // ---------------- P2: parent panel feats -> pfeat ----------------------
    if (coop || mode == 3) {
        if (bx < 32) {
            const int slot = bx * 16 + wid;                  // 0..511
            const int pp = table[slot];
            if (pp >= 0) {
                const int b = slot >> 6;
                const int ptok = b * NS + pp;
                const int pei = ei[ptok], pppi = ppi[ptok];
                const float* ie = iemb + pei * ND;
                const float* pe = pemb + pppi * ND;
                const float* sp = sprj + b * ND;             // global (cross-batch)

                f4 x[3]; float s1 = 0.f, sq = 0.f;
                #pragma unroll
                for (int g = 0; g < 3; ++g) {
                    int i = g*64 + lane;
                    f4 a = ld4(temb + ND, i), c = ld4(ie, i), d = ld4(pe, i), s = ld4(sp, i);
                    f4 v;
                    v.x = a.x + c.x + d.x + s.x;
                    v.y = a.y + c.y + d.y + s.y;
                    v.z = a.z + c.z + d.z + s.z;
                    v.w = a.w + c.w + d.w + s.w;
                    x[g] = v;
                    s1 += v.x + v.y + v.z + v.w;
                    sq = fmaf(v.x, v.x, sq);
                    sq = fmaf(v.y, v.y, sq);
                    sq = fmaf(v.z, v.z, sq);
                    sq = fmaf(v.w, v.w, sq);
                }
                #pragma unroll
                for (int k = 32; k >= 1; k >>= 1) {
                    s1 += __shfl_xor(s1, k, 64);
                    sq += __shfl_xor(sq, k, 64);
                }
                float mu = s1 * (1.f/ND);
                float rs = rsqrtf(sq * (1.f/ND) - mu * mu + 1e-5f);
                float c0 = -mu * rs;
                float* dst = pfeat + (size_t)slot * ND;
                #pragma unroll
                for (int g = 0; g < 3; ++g) {
                    int i = g*64 + lane;
                    f4 gg = S[6144 + i], bb = S[6336 + i];
                    f4 v = x[g], xn;
                    xn.x = fmaf(v.x, rs, c0); v.x = fmaf(xn.x, gg.x, bb.x);
                    xn.y = fmaf(v.y, rs, c0); v.y = fmaf(xn.y, gg.y, bb.y);
                    xn.z = fmaf(v.z, rs, c0); v.z = fmaf(xn.z, gg.z, bb.z);
                    xn.w = fmaf(v.w, rs, c0); v.w = fmaf(xn.w, gg.w, bb.w);
                    ((f4*)dst)[i] = v;
                }
            }
        }
    }
    if (coop) cg::this_grid().sync();

    // ---------------- P3: main, 8 rounds x 16 tokens per block -------------
    if (coop || mode == 4) {
        const int b = bx >> 5;                               // batch (32 blocks/batch)
        for (int r = 0; r < 8; ++r) {
            const int t = bx * 128 + r * 16 + wid;
            const int type = et[t];

            f4 z4; z4.x = 0.f; z4.y = 0.f; z4.z = 0.f; z4.w = 0.f;
            f4 po0 = z4, po1 = z4, dq0 = z4, dq1 = z4, cq0 = z4;

            if (type != 0) {
                const int my_ei = ei[t], my_ppi = ppi[t];
                int pp = -1;
                if (type != 1) pp = table[b * 64 + my_ppi];

                const float* te = temb + type * ND;
                const float* ie = iemb + my_ei * ND;
                const float* pe = pemb + my_ppi * ND;

                f4 x[3];
                float s1 = 0.f, sq = 0.f;
                #pragma unroll
                for (int g = 0; g < 3; ++g) {
                    int i = g * 64 + lane;
                    f4 a = ld4(te, i), c = ld4(ie, i), d = ld4(pe, i);
                    f4 s = S[WPACK_F4 + i];
                    f4 v;
                    v.x = a.x + c.x + d.x + s.x;
                    v.y = a.y + c.y + d.y + s.y;
                    v.z = a.z + c.z + d.z + s.z;
                    v.w = a.w + c.w + d.w + s.w;
                    x[g] = v;
                    s1 += v.x + v.y + v.z + v.w;
                    sq = fmaf(v.x, v.x, sq);
                    sq = fmaf(v.y, v.y, sq);
                    sq = fmaf(v.z, v.z, sq);
                    sq = fmaf(v.w, v.w, sq);
                }
                #pragma unroll
                for (int k = 32; k >= 1; k >>= 1) {
                    s1 += __shfl_xor(s1, k, 64);
                    sq += __shfl_xor(sq, k, 64);
                }
                float mu = s1 * (1.f / ND);
                float rs = rsqrtf(sq * (1.f / ND) - mu * mu + 1e-5f);
                float c0 = -mu * rs;
                #pragma unroll
                for (int g = 0; g < 3; ++g) {
                    int i = g * 64 + lane;
                    f4 gg = S[6144 + i], bb = S[6336 + i];
                    f4 v = x[g], xn;
                    xn.x = fmaf(v.x, rs, c0); v.x = fmaf(xn.x, gg.x, bb.x);
                    xn.y = fmaf(v.y, rs, c0); v.y = fmaf(xn.y, gg.y, bb.y);
                    xn.z = fmaf(v.z, rs, c0); v.z = fmaf(xn.z, gg.z, bb.z);
                    xn.w = fmaf(v.w, rs, c0); v.w = fmaf(xn.w, gg.w, bb.w);
                    x[g] = v;
                }

                if (type == 1) {
                    float acc[8];
                    #pragma unroll
                    for (int o = 0; o < 8; ++o) acc[o] = 0.f;
                    #pragma unroll
                    for (int g = 0; g < 3; ++g) {
                        int i = g * 64 + lane;
                        #pragma unroll
                        for (int o = 0; o < 8; ++o)
                            dot4(acc[o], x[g], S[o * 192 + i]);
                    }
                    #pragma unroll
                    for (int k = 32; k >= 1; k >>= 1) {
                        #pragma unroll
                        for (int o = 0; o < 8; ++o)
                            acc[o] += __shfl_xor(acc[o], k, 64);
                    }
                    po0.x = acc[0] + pb[0]; po0.y = acc[1] + pb[1];
                    po0.z = acc[2] + pb[2]; po0.w = acc[3] + pb[3];
                    po1.x = acc[4] + pb[4]; po1.y = acc[5] + pb[5];
                    po1.z = acc[6] + pb[6]; po1.w = acc[7] + pb[7];
                } else if (pp >= 0) {
                    const float* pfr = pfeat + (size_t)(b * 64 + my_ppi) * ND;
                    if (type == 2) {
                        float acc[8];
                        #pragma unroll
                        for (int o = 0; o < 8; ++o) acc[o] = 0.f;
                        #pragma unroll
                        for (int g = 0; g < 3; ++g) {
                            int i = g * 64 + lane;
                            #pragma unroll
                            for (int o = 0; o < 8; ++o)
                                dot4(acc[o], x[g], S[1536 + o * 384 + i]);
                        }
                        #pragma unroll
                        for (int g = 0; g < 3; ++g)
                            x[g] = ld4(pfr, g * 64 + lane);
                        #pragma unroll
                        for (int g = 0; g < 3; ++g) {
                            int i = g * 64 + lane;
                            #pragma unroll
                            for (int o = 0; o < 8; ++o)
                                dot4(acc[o], x[g], S[1536 + o * 384 + 192 + i]);
                        }
                        #pragma unroll
                        for (int k = 32; k >= 1; k >>= 1) {
                            #pragma unroll
                            for (int o = 0; o < 8; ++o)
                                acc[o] += __shfl_xor(acc[o], k, 64);
                        }
                        dq0.x = acc[0] + db[0]; dq0.y = acc[1] + db[1];
                        dq0.z = acc[2] + db[2]; dq0.w = acc[3] + db[3];
                        dq1.x = acc[4] + db[4]; dq1.y = acc[5] + db[5];
                        dq1.z = acc[6] + db[6]; dq1.w = acc[7] + db[7];
                    } else {
                        float acc[4];
                        #pragma unroll
                        for (int o = 0; o < 4; ++o) acc[o] = 0.f;
                        #pragma unroll
                        for (int g = 0; g < 3; ++g) {
                            int i = g * 64 + lane;
                            #pragma unroll
                            for (int o = 0; o < 4; ++o)
                                dot4(acc[o], x[g], S[4608 + o * 384 + i]);
                        }
                        #pragma unroll
                        for (int g = 0; g < 3; ++g)
                            x[g] = ld4(pfr, g * 64 + lane);
                        #pragma unroll
                        for (int g = 0; g < 3; ++g) {
                            int i = g * 64 + lane;
                            #pragma unroll
                            for (int o = 0; o < 4; ++o)
                                dot4(acc[o], x[g], S[4608 + o * 384 + 192 + i]);
                        }
                        #pragma unroll
                        for (int k = 32; k >= 1; k >>= 1) {
                            #pragma unroll
                            for (int o = 0; o < 4; ++o)
                                acc[o] += __shfl_xor(acc[o], k, 64);
                        }
                        cq0.x = acc[0] + cb[0]; cq0.y = acc[1] + cb[1];
                        cq0.z = acc[2] + cb[2]; cq0.w = acc[3] + cb[3];
                    }
                }
            }

            if (lane == 0) {
                f4* op = (f4*)(out + (size_t)t * 8);
                op[0] = po0; op[1] = po1;
                f4* od = (f4*)(out + (size_t)NB * NS * 8 + (size_t)t * 8);
                od[0] = dq0; od[1] = dq1;
                ((f4*)(out + (size_t)NB * NS * 16 + (size_t)t * 4))[0] = cq0;
            }
        }
    }
}

extern "C" void kernel_launch(void* const* d_in, const int* in_sizes, int n_in,
                              void* d_out, int out_size, void* d_ws, size_t ws_size,
                              hipStream_t stream) {
    const int* et  = (const int*)d_in[0];
    const int* ei  = (const int*)d_in[1];
    const int* ppi = (const int*)d_in[2];
    const float* sv   = (const float*)d_in[3];
    const float* temb = (const float*)d_in[4];
    const float* iemb = (const float*)d_in[5];
    const float* pemb = (const float*)d_in[6];
    const float* sw   = (const float*)d_in[7];
    const float* sb   = (const float*)d_in[8];
    const float* lng  = (const float*)d_in[9];
    const float* lnb  = (const float*)d_in[10];
    const float* pw   = (const float*)d_in[11];
    const float* pb   = (const float*)d_in[12];
    const float* dw   = (const float*)d_in[13];
    const float* db   = (const float*)d_in[14];
    const float* cw   = (const float*)d_in[15];
    const float* cbp  = (const float*)d_in[16];
    float* out = (float*)d_out;

    // ws layout: [0,2KB) table | [4KB,28KB) sproj | [32KB,+104448B) wpack
    //            | then pfeat (512x768 f32 = 1.5MB)
    int*   table = (int*)d_ws;
    float* sprj  = (float*)((char*)d_ws + 4096);
    float* wpack = (float*)((char*)d_ws + 32768);
    float* pfeat = (float*)((char*)d_ws + 32768 + WPACK_F4 * 16);

    int mode = 0;
    void* args[] = { (void*)&et, (void*)&ei, (void*)&ppi, (void*)&sv,
                     (void*)&temb, (void*)&iemb, (void*)&pemb,
                     (void*)&sw, (void*)&sb, (void*)&lng, (void*)&lnb,
                     (void*)&pw, (void*)&pb, (void*)&dw, (void*)&db,
                     (void*)&cw, (void*)&cbp,
                     (void*)&table, (void*)&sprj, (void*)&wpack, (void*)&pfeat,
                     (void*)&out, (void*)&mode };
    hipError_t e = hipLaunchCooperativeKernel((void*)lp_all, dim3(256), dim3(1024),
                                              args, 0, stream);
    if (e != hipSuccess) {
        // fallback: same kernel as 4 standalone phases
        lp_all<<<8,   1024, 0, stream>>>(et, ei, ppi, sv, temb, iemb, pemb, sw, sb,
                                         lng, lnb, pw, pb, dw, db, cw, cbp,
                                         table, sprj, wpack, pfeat, out, 1);
        lp_all<<<32,  1024, 0, stream>>>(et, ei, ppi, sv, temb, iemb, pemb, sw, sb,
                                         lng, lnb, pw, pb, dw, db, cw, cbp,
                                         table, sprj, wpack, pfeat, out, 2);
        lp_all<<<32,  1024, 0, stream>>>(et, ei, ppi, sv, temb, iemb, pemb, sw, sb,
                                         lng, lnb, pw, pb, dw, db, cw, cbp,
                                         table, sprj, wpack, pfeat, out, 3);
        lp_all<<<256, 1024, 0, stream>>>(et, ei, ppi, sv, temb, iemb, pemb, sw, sb,
                                         lng, lnb, pw, pb, dw, db, cw, cbp,
                                         table, sprj, wpack, pfeat, out, 4);
    }
}

// Round 5
// 129.873 us; speedup vs baseline: 1.7321x; 1.7321x over previous
//
#include <hip/hip_runtime.h>

#define NB 8
#define NS 4096
#define ND 768

// packed-f4 layout inside wpack / LDS (units of float4):
//   [0,1536)    panel weights  : o*192 + i
//   [1536,4608) dialog weights : 1536 + o*384 + i  (+192 = parent half)
//   [4608,6144) char weights   : 4608 + o*384 + i  (+192 = parent half)
//   [6144,6336) lng | [6336,6528) lnb | [6528,6720) this block's sprj row
#define WPACK_F4 6528
#define LDS_F4   6720

typedef float4 f4;

static __device__ __forceinline__ f4 ld4(const float* __restrict__ p, int i) {
    return ((const f4*)p)[i];
}

static __device__ __forceinline__ void dot4(float& acc, const f4& a, const f4& w) {
    acc = fmaf(a.x, w.x, acc);
    acc = fmaf(a.y, w.y, acc);
    acc = fmaf(a.z, w.z, acc);
    acc = fmaf(a.w, w.w, acc);
}

// ---------------------------------------------------------------------------
// Kernel 1 (lp_pre):
//   blocks   0..127 : scatter-max parent table (last panel occurrence wins)
//   blocks 128..129 : per-batch style projection (8 waves)
//   blocks 130..155 : pack head weights + ln params into wpack (contiguous)
// ---------------------------------------------------------------------------
__global__ __launch_bounds__(256) void lp_pre(
    const int* __restrict__ et, const int* __restrict__ ei,
    const float* __restrict__ sv, const float* __restrict__ sw,
    const float* __restrict__ sb,
    const float* __restrict__ pw, const float* __restrict__ dw,
    const float* __restrict__ cw,
    const float* __restrict__ lng, const float* __restrict__ lnb,
    int* __restrict__ table, float* __restrict__ sprj,
    float* __restrict__ wpack)
{
    const int bx = blockIdx.x;
    if (bx < 128) {
        int t = bx * 256 + threadIdx.x;
        if (et[t] == 1) {
            int b = t >> 12;
            atomicMax(&table[b * 64 + ei[t]], t & (NS - 1));
        }
    } else if (bx < 130) {
        const int lane = threadIdx.x & 63;
        const int b = (bx - 128) * 4 + (threadIdx.x >> 6);   // 0..7
        const float sv0 = sv[b*4+0], sv1 = sv[b*4+1], sv2 = sv[b*4+2], sv3 = sv[b*4+3];
        #pragma unroll
        for (int g = 0; g < 3; ++g) {
            int i = g*64 + lane;
            f4 w0 = ld4(sw, i), w1 = ld4(sw, 192+i), w2 = ld4(sw, 384+i), w3 = ld4(sw, 576+i);
            f4 bb = ld4(sb, i);
            f4 r;
            r.x = bb.x + sv0*w0.x + sv1*w1.x + sv2*w2.x + sv3*w3.x;
            r.y = bb.y + sv0*w0.y + sv1*w1.y + sv2*w2.y + sv3*w3.y;
            r.z = bb.z + sv0*w0.z + sv1*w1.z + sv2*w2.z + sv3*w3.z;
            r.w = bb.w + sv0*w0.w + sv1*w1.w + sv2*w2.w + sv3*w3.w;
            ((f4*)(sprj + b*ND))[i] = r;
        }
    } else {
        const int q = (bx - 130) * 256 + threadIdx.x;   // 0..6655
        if (q >= WPACK_F4) return;
        f4 r;
        if (q < 1536) {                                  // panel: 8 x 192
            int o = q / 192, i = q - o * 192, d0 = 4 * i;
            r.x = pw[(d0+0)*8 + o];
            r.y = pw[(d0+1)*8 + o];
            r.z = pw[(d0+2)*8 + o];
            r.w = pw[(d0+3)*8 + o];
        } else if (q < 4608) {                           // dialog: 8 x 384
            int u = q - 1536;
            int o = u / 384, i = u - o * 384;
            int d0 = (i < 192) ? 4*i : 768 + 4*(i - 192);
            r.x = dw[(d0+0)*8 + o];
            r.y = dw[(d0+1)*8 + o];
            r.z = dw[(d0+2)*8 + o];
            r.w = dw[(d0+3)*8 + o];
        } else if (q < 6144) {                           // char: 4 x 384
            int u = q - 4608;
            int o = u / 384, i = u - o * 384;
            int d0 = (i < 192) ? 4*i : 768 + 4*(i - 192);
            r.x = cw[(d0+0)*4 + o];
            r.y = cw[(d0+1)*4 + o];
            r.z = cw[(d0+2)*4 + o];
            r.w = cw[(d0+3)*4 + o];
        } else if (q < 6336) {                           // lng
            r = ld4(lng, q - 6144);
        } else {                                         // lnb
            r = ld4(lnb, q - 6336);
        }
        ((f4*)wpack)[q] = r;
    }
}

// ---------------------------------------------------------------------------
// Kernel 2 (lp_parent): one wave per (b, slot); NORMALIZED parent feats.
// ---------------------------------------------------------------------------
__global__ __launch_bounds__(256) void lp_parent(
    const int* __restrict__ ei, const int* __restrict__ ppi,
    const float* __restrict__ temb, const float* __restrict__ iemb,
    const float* __restrict__ pemb, const float* __restrict__ lng,
    const float* __restrict__ lnb,
    const int* __restrict__ table, const float* __restrict__ sprj,
    float* __restrict__ pfeat)
{
    const int lane = threadIdx.x & 63;
    const int slot = blockIdx.x * 4 + (threadIdx.x >> 6);   // 0..511
    const int b = slot >> 6;
    const int pp = table[slot];
    if (pp < 0) return;                                     // wave-uniform
    const int ptok = b * NS + pp;
    const int pei = ei[ptok], pppi = ppi[ptok];
    const float* ie = iemb + pei * ND;
    const float* pe = pemb + pppi * ND;
    const float* sp = sprj + b * ND;

    f4 x[3]; float s1 = 0.f, sq = 0.f;
    #pragma unroll
    for (int g = 0; g < 3; ++g) {
        int i = g*64 + lane;
        f4 a = ld4(temb + ND, i), c = ld4(ie, i), d = ld4(pe, i), s = ld4(sp, i);
        f4 v;
        v.x = a.x + c.x + d.x + s.x;
        v.y = a.y + c.y + d.y + s.y;
        v.z = a.z + c.z + d.z + s.z;
        v.w = a.w + c.w + d.w + s.w;
        x[g] = v;
        s1 += v.x + v.y + v.z + v.w;
        sq = fmaf(v.x, v.x, sq);
        sq = fmaf(v.y, v.y, sq);
        sq = fmaf(v.z, v.z, sq);
        sq = fmaf(v.w, v.w, sq);
    }
    #pragma unroll
    for (int k = 32; k >= 1; k >>= 1) {
        s1 += __shfl_xor(s1, k, 64);
        sq += __shfl_xor(sq, k, 64);
    }
    float mu = s1 * (1.f/ND);
    float rs = rsqrtf(sq * (1.f/ND) - mu * mu + 1e-5f);
    float c0 = -mu * rs;
    float* dst = pfeat + (size_t)slot * ND;
    #pragma unroll
    for (int g = 0; g < 3; ++g) {
        int i = g*64 + lane;
        f4 gg = ld4(lng, i), bb = ld4(lnb, i);
        f4 v = x[g], xn;
        xn.x = fmaf(v.x, rs, c0); v.x = fmaf(xn.x, gg.x, bb.x);
        xn.y = fmaf(v.y, rs, c0); v.y = fmaf(xn.y, gg.y, bb.y);
        xn.z = fmaf(v.z, rs, c0); v.z = fmaf(xn.z, gg.z, bb.z);
        xn.w = fmaf(v.w, rs, c0); v.w = fmaf(xn.w, gg.w, bb.w);
        ((f4*)dst)[i] = v;
    }
}

// ---------------------------------------------------------------------------
// Kernel 3 (lp_main): PERSISTENT. 256 blocks x 1024 threads = 1 block/CU
// (107 KB LDS). Stage all weights ONCE, then each wave loops over 8 tokens
// with no barrier in the loop (cross-token ILP; next token's scalar indices
// prefetched one iteration ahead so embedding gathers issue early).
// ---------------------------------------------------------------------------
__global__ __launch_bounds__(1024) void lp_main(
    const int* __restrict__ et, const int* __restrict__ ei, const int* __restrict__ ppi,
    const float* __restrict__ temb, const float* __restrict__ iemb,
    const float* __restrict__ pemb,
    const float* __restrict__ pb, const float* __restrict__ db,
    const float* __restrict__ cb,
    const int* __restrict__ table, const float* __restrict__ sprj,
    const float* __restrict__ wpack, const float* __restrict__ pfeat,
    float* __restrict__ out)
{
    __shared__ f4 S[LDS_F4];                 // 107,520 B -> 1 block/CU
    const int tid = threadIdx.x;
    const int lane = tid & 63;
    const int wid = tid >> 6;                // 0..15
    const int bx = blockIdx.x;               // 0..255
    const int b = bx >> 5;                   // 32 blocks per batch

    // ---- stage weights + ln + style row into LDS once ----
    for (int i = tid; i < WPACK_F4; i += 1024) S[i] = ((const f4*)wpack)[i];
    if (tid < 192) S[WPACK_F4 + tid] = ((const f4*)(sprj + b * ND))[tid];
    __syncthreads();

    // ---- prefetch scalars for first token ----
    int t = bx * 128 + wid;
    int type = et[t], my_ei = ei[t], my_ppi = ppi[t];

    for (int r = 0; r < 8; ++r) {
        // prefetch next token's scalars (breaks index->gather dependency)
        const int tn = t + 16;
        int type_n = 0, ei_n = 0, ppi_n = 0;
        if (r < 7) { type_n = et[tn]; ei_n = ei[tn]; ppi_n = ppi[tn]; }

        f4 z4; z4.x = 0.f; z4.y = 0.f; z4.z = 0.f; z4.w = 0.f;
        f4 po0 = z4, po1 = z4, dq0 = z4, dq1 = z4, cq0 = z4;

        if (type != 0) {
            int pp = -1;
            if (type != 1) pp = table[b * 64 + my_ppi];   // issue early

            const float* te = temb + type * ND;
            const float* ie = iemb + my_ei * ND;
            const float* pe = pemb + my_ppi * ND;

            // --- own feats: embedding sum + style proj, single-pass stats ---
            f4 x[3];
            float s1 = 0.f, sq = 0.f;
            #pragma unroll
            for (int g = 0; g < 3; ++g) {
                int i = g * 64 + lane;
                f4 a = ld4(te, i), c = ld4(ie, i), d = ld4(pe, i);
                f4 s = S[WPACK_F4 + i];
                f4 v;
                v.x = a.x + c.x + d.x + s.x;
                v.y = a.y + c.y + d.y + s.y;
                v.z = a.z + c.z + d.z + s.z;
                v.w = a.w + c.w + d.w + s.w;
                x[g] = v;
                s1 += v.x + v.y + v.z + v.w;
                sq = fmaf(v.x, v.x, sq);
                sq = fmaf(v.y, v.y, sq);
                sq = fmaf(v.z, v.z, sq);
                sq = fmaf(v.w, v.w, sq);
            }
            #pragma unroll
            for (int k = 32; k >= 1; k >>= 1) {
                s1 += __shfl_xor(s1, k, 64);
                sq += __shfl_xor(sq, k, 64);
            }
            float mu = s1 * (1.f / ND);
            float rs = rsqrtf(sq * (1.f / ND) - mu * mu + 1e-5f);
            float c0 = -mu * rs;
            #pragma unroll
            for (int g = 0; g < 3; ++g) {
                int i = g * 64 + lane;
                f4 gg = S[6144 + i], bb = S[6336 + i];
                f4 v = x[g], xn;
                xn.x = fmaf(v.x, rs, c0); v.x = fmaf(xn.x, gg.x, bb.x);
                xn.y = fmaf(v.y, rs, c0); v.y = fmaf(xn.y, gg.y, bb.y);
                xn.z = fmaf(v.z, rs, c0); v.z = fmaf(xn.z, gg.z, bb.z);
                xn.w = fmaf(v.w, rs, c0); v.w = fmaf(xn.w, gg.w, bb.w);
                x[g] = v;
            }

            if (type == 1) {
                float acc[8];
                #pragma unroll
                for (int o = 0; o < 8; ++o) acc[o] = 0.f;
                #pragma unroll
                for (int g = 0; g < 3; ++g) {
                    int i = g * 64 + lane;
                    #pragma unroll
                    for (int o = 0; o < 8; ++o)
                        dot4(acc[o], x[g], S[o * 192 + i]);
                }
                #pragma unroll
                for (int k = 32; k >= 1; k >>= 1) {
                    #pragma unroll
                    for (int o = 0; o < 8; ++o)
                        acc[o] += __shfl_xor(acc[o], k, 64);
                }
                po0.x = acc[0] + pb[0]; po0.y = acc[1] + pb[1];
                po0.z = acc[2] + pb[2]; po0.w = acc[3] + pb[3];
                po1.x = acc[4] + pb[4]; po1.y = acc[5] + pb[5];
                po1.z = acc[6] + pb[6]; po1.w = acc[7] + pb[7];
            } else if (pp >= 0) {
                const float* pfr = pfeat + (size_t)(b * 64 + my_ppi) * ND;
                if (type == 2) {
                    float acc[8];
                    #pragma unroll
                    for (int o = 0; o < 8; ++o) acc[o] = 0.f;
                    #pragma unroll
                    for (int g = 0; g < 3; ++g) {
                        int i = g * 64 + lane;
                        #pragma unroll
                        for (int o = 0; o < 8; ++o)
                            dot4(acc[o], x[g], S[1536 + o * 384 + i]);
                    }
                    #pragma unroll
                    for (int g = 0; g < 3; ++g)
                        x[g] = ld4(pfr, g * 64 + lane);
                    #pragma unroll
                    for (int g = 0; g < 3; ++g) {
                        int i = g * 64 + lane;
                        #pragma unroll
                        for (int o = 0; o < 8; ++o)
                            dot4(acc[o], x[g], S[1536 + o * 384 + 192 + i]);
                    }
                    #pragma unroll
                    for (int k = 32; k >= 1; k >>= 1) {
                        #pragma unroll
                        for (int o = 0; o < 8; ++o)
                            acc[o] += __shfl_xor(acc[o], k, 64);
                    }
                    dq0.x = acc[0] + db[0]; dq0.y = acc[1] + db[1];
                    dq0.z = acc[2] + db[2]; dq0.w = acc[3] + db[3];
                    dq1.x = acc[4] + db[4]; dq1.y = acc[5] + db[5];
                    dq1.z = acc[6] + db[6]; dq1.w = acc[7] + db[7];
                } else {
                    float acc[4];
                    #pragma unroll
                    for (int o = 0; o < 4; ++o) acc[o] = 0.f;
                    #pragma unroll
                    for (int g = 0; g < 3; ++g) {
                        int i = g * 64 + lane;
                        #pragma unroll
                        for (int o = 0; o < 4; ++o)
                            dot4(acc[o], x[g], S[4608 + o * 384 + i]);
                    }
                    #pragma unroll
                    for (int g = 0; g < 3; ++g)
                        x[g] = ld4(pfr, g * 64 + lane);
                    #pragma unroll
                    for (int g = 0; g < 3; ++g) {
                        int i = g * 64 + lane;
                        #pragma unroll
                        for (int o = 0; o < 4; ++o)
                            dot4(acc[o], x[g], S[4608 + o * 384 + 192 + i]);
                    }
                    #pragma unroll
                    for (int k = 32; k >= 1; k >>= 1) {
                        #pragma unroll
                        for (int o = 0; o < 4; ++o)
                            acc[o] += __shfl_xor(acc[o], k, 64);
                    }
                    cq0.x = acc[0] + cb[0]; cq0.y = acc[1] + cb[1];
                    cq0.z = acc[2] + cb[2]; cq0.w = acc[3] + cb[3];
                }
            }
        }

        // every wave writes its 20 outputs (zeros for masked / type-0 tokens)
        if (lane == 0) {
            f4* op = (f4*)(out + (size_t)t * 8);
            op[0] = po0; op[1] = po1;
            f4* od = (f4*)(out + (size_t)NB * NS * 8 + (size_t)t * 8);
            od[0] = dq0; od[1] = dq1;
            ((f4*)(out + (size_t)NB * NS * 16 + (size_t)t * 4))[0] = cq0;
        }

        t = tn; type = type_n; my_ei = ei_n; my_ppi = ppi_n;
    }
}

extern "C" void kernel_launch(void* const* d_in, const int* in_sizes, int n_in,
                              void* d_out, int out_size, void* d_ws, size_t ws_size,
                              hipStream_t stream) {
    const int* et  = (const int*)d_in[0];
    const int* ei  = (const int*)d_in[1];
    const int* ppi = (const int*)d_in[2];
    const float* sv   = (const float*)d_in[3];
    const float* temb = (const float*)d_in[4];
    const float* iemb = (const float*)d_in[5];
    const float* pemb = (const float*)d_in[6];
    const float* sw   = (const float*)d_in[7];
    const float* sb   = (const float*)d_in[8];
    const float* lng  = (const float*)d_in[9];
    const float* lnb  = (const float*)d_in[10];
    const float* pw   = (const float*)d_in[11];
    const float* pb   = (const float*)d_in[12];
    const float* dw   = (const float*)d_in[13];
    const float* db   = (const float*)d_in[14];
    const float* cw   = (const float*)d_in[15];
    const float* cbp  = (const float*)d_in[16];
    float* out = (float*)d_out;

    // ws layout: [0,2KB) table | [4KB,28KB) sproj | [32KB,+104448B) wpack
    //            | then pfeat (512x768 f32 = 1.5MB)
    int*   table = (int*)d_ws;
    float* sprj  = (float*)((char*)d_ws + 4096);
    float* wpack = (float*)((char*)d_ws + 32768);
    float* pfeat = (float*)((char*)d_ws + 32768 + WPACK_F4 * 16);

    hipMemsetAsync(table, 0xFF, NB * 64 * sizeof(int), stream);  // all -1

    lp_pre<<<156, 256, 0, stream>>>(et, ei, sv, sw, sb, pw, dw, cw, lng, lnb,
                                    table, sprj, wpack);
    lp_parent<<<128, 256, 0, stream>>>(ei, ppi, temb, iemb, pemb, lng, lnb,
                                       table, sprj, pfeat);
    lp_main<<<256, 1024, 0, stream>>>(et, ei, ppi, temb, iemb, pemb,
                                      pb, db, cbp,
                                      table, sprj, wpack, pfeat, out);
}